// Round 6
// baseline (109.322 us; speedup 1.0000x reference)
//
#include <hip/hip_runtime.h>
#include <math.h>

// ROUND-6 CALIBRATION BUILD: round-1 kernels verbatim, each launched TWICE.
// All kernels are idempotent pure functions of their inputs, so duplicated
// launches produce identical buffers and the final output is unchanged.
// dur_us(R6) = F + 2K vs dur_us(R1)=57.2 = F + K  ->  K = R6 - 57.2.

// Problem constants (fixed by harness)
#define NN   128
#define TT   1024
#define SS   1024
#define H1D  512
#define H2D  128
#define OUTD 8
#define TCH  4      // t-chunks for NUDFT split
#define TC   256    // t per chunk

// ws layout in floats (~6.03 MB)
#define OFF_RE   0
#define OFF_IM   (TCH*NN*SS)                  //  524288
#define OFF_FREQ (2*TCH*NN*SS)                // 1048576
#define OFF_P1   (OFF_FREQ + NN*SS)           // 1179648
#define OFF_H1   (OFF_P1 + 4*NN*H1D)          // 1441792  (end 1507328 floats)

__device__ __forceinline__ float cos_rev(float r) { return __builtin_amdgcn_cosf(r); } // cos(2*pi*r)
__device__ __forceinline__ float sin_rev(float r) { return __builtin_amdgcn_sinf(r); } // sin(2*pi*r)

// ---------------------------------------------------------------------------
// Kernel 1: partial NUDFT (round-1 verbatim)
// ---------------------------------------------------------------------------
__global__ __launch_bounds__(256) void k_nudft(const float* __restrict__ inp,
                                               float* __restrict__ ws) {
    const int tc  = blockIdx.x;   // 0..3
    const int n   = blockIdx.y;   // 0..127
    const int tid = threadIdx.x;  // 0..255

    __shared__ float4 sh[TC];     // {frac(day), x, cos(2pi d), sin(2pi d)}
    {
        const int t = tc * TC + tid;
        const float* p = inp + (size_t)(n * TT + t) * 3;
        const float x  = p[0];
        const float d  = p[2];
        const float df = d - floorf(d);            // exact for |d| < 2^23
        sh[tid] = make_float4(df, x, cos_rev(df), sin_rev(df));
    }
    __syncthreads();

    const float s0f = (float)(tid * 4);
    float re0 = 0.f, re1 = 0.f, re2 = 0.f, re3 = 0.f;
    float im0 = 0.f, im1 = 0.f, im2 = 0.f, im3 = 0.f;

#pragma unroll 2
    for (int i = 0; i < TC; ++i) {
        const float4 v = sh[i];                    // broadcast read
        const float p   = s0f * v.x;
        const float plo = fmaf(s0f, v.x, -p);      // exact product residual
        const float r   = (p - floorf(p)) + plo;
        float c  = cos_rev(r);
        float sn = sin_rev(r);
        re0 = fmaf(v.y, c, re0);  im0 = fmaf(v.y, sn, im0);
        float c2  = fmaf(-sn, v.w, c * v.z);
        float sn2 = fmaf( c,  v.w, sn * v.z);
        re1 = fmaf(v.y, c2, re1); im1 = fmaf(v.y, sn2, im1);
        float c3  = fmaf(-sn2, v.w, c2 * v.z);
        float sn3 = fmaf( c2,  v.w, sn2 * v.z);
        re2 = fmaf(v.y, c3, re2); im2 = fmaf(v.y, sn3, im2);
        float c4  = fmaf(-sn3, v.w, c3 * v.z);
        float sn4 = fmaf( c3,  v.w, sn3 * v.z);
        re3 = fmaf(v.y, c4, re3); im3 = fmaf(v.y, sn4, im3);
    }

    const size_t base4 = (((size_t)(tc * NN + n)) * SS + tid * 4) >> 2;
    float4* RE = (float4*)(ws + OFF_RE);
    float4* IM = (float4*)(ws + OFF_IM);
    RE[base4] = make_float4(re0, re1, re2, re3);
    IM[base4] = make_float4(im0, im1, im2, im3);
}

// ---------------------------------------------------------------------------
// Kernel 2: combine t-chunk partials -> frequential (round-1 verbatim)
// ---------------------------------------------------------------------------
__global__ __launch_bounds__(256) void k_combine1(float* __restrict__ ws) {
    const int tid = blockIdx.x * 256 + threadIdx.x;   // 0..131071 (= n*SS + s)
    const int n = tid >> 10, s = tid & 1023;
    float re = 0.f, im = 0.f;
    for (int tc = 0; tc < TCH; ++tc) {
        const size_t o = ((size_t)(tc * NN + n)) * SS + s;
        re += ws[OFF_RE + o];
        im += ws[OFF_IM + o];
    }
    ws[OFF_FREQ + tid] = sqrtf(fmaf(re, re, im * im));
}

// ---------------------------------------------------------------------------
// Kernel 3: layer-1 split-K partial GEMM (round-1 verbatim)
// ---------------------------------------------------------------------------
__global__ __launch_bounds__(256) void k_l1p(const float* __restrict__ W1,
                                             float* __restrict__ ws) {
    const int kq = blockIdx.x;   // 0..3   k-chunk of 256
    const int jq = blockIdx.y;   // 0..3   j-chunk of 128
    const int nb = blockIdx.z;   // 0..15  n-chunk of 8
    const int tid = threadIdx.x;

    __shared__ float4 Al[8][64];  // 8 n-rows x 256 k (as float4)
    const float4* FQ = (const float4*)(ws + OFF_FREQ);
#pragma unroll
    for (int v = 0; v < 2; ++v) {
        const int idx = v * 256 + tid;
        const int row = idx >> 6, c4 = idx & 63;
        Al[row][c4] = FQ[(nb * 8 + row) * 256 + kq * 64 + c4];
    }
    __syncthreads();

    const int jl = tid & 127, ng = tid >> 7;
    const int j = jq * 128 + jl;
    const float4* W1v = (const float4*)W1;
    float a0 = 0.f, a1 = 0.f, a2 = 0.f, a3 = 0.f;
#pragma unroll 4
    for (int k4 = 0; k4 < 64; ++k4) {
        const float4 w  = W1v[(size_t)j * 256 + kq * 64 + k4];
        const float4 x0 = Al[ng * 4 + 0][k4];
        const float4 x1 = Al[ng * 4 + 1][k4];
        const float4 x2 = Al[ng * 4 + 2][k4];
        const float4 x3 = Al[ng * 4 + 3][k4];
        a0 = fmaf(x0.x, w.x, fmaf(x0.y, w.y, fmaf(x0.z, w.z, fmaf(x0.w, w.w, a0))));
        a1 = fmaf(x1.x, w.x, fmaf(x1.y, w.y, fmaf(x1.z, w.z, fmaf(x1.w, w.w, a1))));
        a2 = fmaf(x2.x, w.x, fmaf(x2.y, w.y, fmaf(x2.z, w.z, fmaf(x2.w, w.w, a2))));
        a3 = fmaf(x3.x, w.x, fmaf(x3.y, w.y, fmaf(x3.z, w.z, fmaf(x3.w, w.w, a3))));
    }
    float* P1 = ws + OFF_P1;
    const float acc[4] = {a0, a1, a2, a3};
#pragma unroll
    for (int i = 0; i < 4; ++i)
        P1[((size_t)(kq * NN + nb * 8 + ng * 4 + i)) * H1D + j] = acc[i];
}

// ---------------------------------------------------------------------------
// Kernel 4: combine layer-1 split-K partials + bias + sigmoid (round-1 verbatim)
// ---------------------------------------------------------------------------
__global__ __launch_bounds__(256) void k_l1c(const float* __restrict__ b1,
                                             float* __restrict__ ws) {
    const int tid = blockIdx.x * 256 + threadIdx.x;   // 0..65535 (= n*H1D + j)
    const int j = tid & (H1D - 1);
    float s = b1[j];
    for (int kq = 0; kq < 4; ++kq) s += ws[OFF_P1 + (size_t)kq * (NN * H1D) + tid];
    ws[OFF_H1 + tid] = 1.0f / (1.0f + __expf(-s));
}

// ---------------------------------------------------------------------------
// Kernel 5: fused layers 2+3 (round-1 verbatim)
// ---------------------------------------------------------------------------
__global__ __launch_bounds__(128) void k_l23(const float* __restrict__ W2,
                                             const float* __restrict__ b2,
                                             const float* __restrict__ W3,
                                             const float* __restrict__ b3,
                                             const float* __restrict__ ws,
                                             float* __restrict__ out) {
    const int n = blockIdx.x;
    const int j = threadIdx.x;   // 0..127

    __shared__ float4 h1l[128];  // h1 row (512 floats)
    __shared__ float  h2l[128];
    h1l[j] = ((const float4*)(ws + OFF_H1))[n * 128 + j];
    __syncthreads();

    const float4* W2v = (const float4*)W2;
    float a = b2[j];
#pragma unroll 4
    for (int k = 0; k < 128; ++k) {
        const float4 h = h1l[k];                    // broadcast
        const float4 w = W2v[(size_t)j * 128 + k];
        a = fmaf(h.x, w.x, fmaf(h.y, w.y, fmaf(h.z, w.z, fmaf(h.w, w.w, a))));
    }
    h2l[j] = 1.0f / (1.0f + __expf(-a));
    __syncthreads();

    if (j < OUTD) {
        float acc = b3[j];
        for (int q = 0; q < H2D; ++q) acc = fmaf(h2l[q], W3[j * H2D + q], acc);
        out[n * OUTD + j] = acc;
    }
}

extern "C" void kernel_launch(void* const* d_in, const int* in_sizes, int n_in,
                              void* d_out, int out_size, void* d_ws, size_t ws_size,
                              hipStream_t stream) {
    (void)in_sizes; (void)n_in; (void)out_size; (void)ws_size;
    const float* inp = (const float*)d_in[0];
    const float* W1  = (const float*)d_in[1];
    const float* b1  = (const float*)d_in[2];
    const float* W2  = (const float*)d_in[3];
    const float* b2  = (const float*)d_in[4];
    const float* W3  = (const float*)d_in[5];
    const float* b3  = (const float*)d_in[6];
    float* out = (float*)d_out;
    float* ws  = (float*)d_ws;

    // Pipeline launched TWICE (calibration: dur = F + 2K). Idempotent.
    for (int rep = 0; rep < 2; ++rep) {
        k_nudft   <<<dim3(TCH, NN), dim3(256), 0, stream>>>(inp, ws);
        k_combine1<<<dim3(512),     dim3(256), 0, stream>>>(ws);
        k_l1p     <<<dim3(4, 4, 16),dim3(256), 0, stream>>>(W1, ws);
        k_l1c     <<<dim3(256),     dim3(256), 0, stream>>>(b1, ws);
        k_l23     <<<dim3(128),     dim3(128), 0, stream>>>(W2, b2, W3, b3, ws, out);
    }
}

// Round 7
// 61.767 us; speedup vs baseline: 1.7699x; 1.7699x over previous
//
#include <hip/hip_runtime.h>
#include <math.h>

// Problem constants (fixed by harness)
#define NN   128
#define TT   1024
#define SS   1024
#define H1D  512
#define H2D  128
#define OUTD 8
#define TCH  4      // t-chunks for NUDFT split (round-1 proven config)
#define TC   256    // t per chunk
#define KQN  8      // layer-1 split-K chunks (K=1024 -> 128 each)

// ws layout in floats (~9.2 MB)
#define OFF_RE   0
#define OFF_IM   (TCH*NN*SS)                  //  524288
#define OFF_FREQ (2*TCH*NN*SS)                // 1048576
#define OFF_W1T  (OFF_FREQ + NN*SS)           // 1179648: W1T [1024 k][512 j]
#define OFF_P1   (OFF_W1T + SS*H1D)           // 1703936: P1 [8 kq][128 n * 512 j]
#define OFF_H1   (OFF_P1 + KQN*NN*H1D)        // 2228224  (end 2293760)

__device__ __forceinline__ float cos_rev(float r) { return __builtin_amdgcn_cosf(r); } // cos(2*pi*r)
__device__ __forceinline__ float sin_rev(float r) { return __builtin_amdgcn_sinf(r); } // sin(2*pi*r)

// ---------------------------------------------------------------------------
// Kernel 1: partial NUDFT — BIT-IDENTICAL to round-1 (unchanged this round;
// total-dur delta attributes n1 = dur - 10.1us per the calibration algebra).
// ---------------------------------------------------------------------------
__global__ __launch_bounds__(256) void k_nudft(const float* __restrict__ inp,
                                               float* __restrict__ ws) {
    const int tc  = blockIdx.x;   // 0..3
    const int n   = blockIdx.y;   // 0..127
    const int tid = threadIdx.x;  // 0..255

    __shared__ float4 sh[TC];     // {frac(day), x, cos(2pi d), sin(2pi d)}
    {
        const int t = tc * TC + tid;
        const float* p = inp + (size_t)(n * TT + t) * 3;
        const float x  = p[0];
        const float d  = p[2];
        const float df = d - floorf(d);            // exact for |d| < 2^23
        sh[tid] = make_float4(df, x, cos_rev(df), sin_rev(df));
    }
    __syncthreads();

    const float s0f = (float)(tid * 4);
    float re0 = 0.f, re1 = 0.f, re2 = 0.f, re3 = 0.f;
    float im0 = 0.f, im1 = 0.f, im2 = 0.f, im3 = 0.f;

#pragma unroll 2
    for (int i = 0; i < TC; ++i) {
        const float4 v = sh[i];                    // broadcast read
        const float p   = s0f * v.x;
        const float plo = fmaf(s0f, v.x, -p);      // exact product residual
        const float r   = (p - floorf(p)) + plo;
        float c  = cos_rev(r);
        float sn = sin_rev(r);
        re0 = fmaf(v.y, c, re0);  im0 = fmaf(v.y, sn, im0);
        float c2  = fmaf(-sn, v.w, c * v.z);
        float sn2 = fmaf( c,  v.w, sn * v.z);
        re1 = fmaf(v.y, c2, re1); im1 = fmaf(v.y, sn2, im1);
        float c3  = fmaf(-sn2, v.w, c2 * v.z);
        float sn3 = fmaf( c2,  v.w, sn2 * v.z);
        re2 = fmaf(v.y, c3, re2); im2 = fmaf(v.y, sn3, im2);
        float c4  = fmaf(-sn3, v.w, c3 * v.z);
        float sn4 = fmaf( c3,  v.w, sn3 * v.z);
        re3 = fmaf(v.y, c4, re3); im3 = fmaf(v.y, sn4, im3);
    }

    const size_t base4 = (((size_t)(tc * NN + n)) * SS + tid * 4) >> 2;
    float4* RE = (float4*)(ws + OFF_RE);
    float4* IM = (float4*)(ws + OFF_IM);
    RE[base4] = make_float4(re0, re1, re2, re3);
    IM[base4] = make_float4(im0, im1, im2, im3);
}

// ---------------------------------------------------------------------------
// Kernel 2: combine partials -> frequential (round-1 verbatim)
// ---------------------------------------------------------------------------
__global__ __launch_bounds__(256) void k_combine1(float* __restrict__ ws) {
    const int tid = blockIdx.x * 256 + threadIdx.x;   // = n*SS + s
    const int n = tid >> 10, s = tid & 1023;
    float re = 0.f, im = 0.f;
    for (int tc = 0; tc < TCH; ++tc) {
        const size_t o = ((size_t)(tc * NN + n)) * SS + s;
        re += ws[OFF_RE + o];
        im += ws[OFF_IM + o];
    }
    ws[OFF_FREQ + tid] = sqrtf(fmaf(re, re, im * im));
}

// ---------------------------------------------------------------------------
// Kernel 3 (NEW): scalar transpose W1 [512 j][1024 k] -> W1T [1024 k][512 j].
// LDS 64x65 tile: global loads coalesced along k, stores coalesced along j,
// LDS reads stride-65 (bank = c+r mod 32: 2-way, free).
// ---------------------------------------------------------------------------
__global__ __launch_bounds__(256) void k_trans(const float* __restrict__ W1,
                                               float* __restrict__ ws) {
    const int jt = blockIdx.x;   // 0..7   (64 j)
    const int kt = blockIdx.y;   // 0..15  (64 k)
    const int tid = threadIdx.x;
    const int c = tid & 63, r0 = tid >> 6;   // 4 rows per pass

    __shared__ float tile[64][65];
    float* W1T = ws + OFF_W1T;
#pragma unroll
    for (int pass = 0; pass < 16; ++pass) {
        const int r = pass * 4 + r0;
        tile[r][c] = W1[(size_t)(jt * 64 + r) * 1024 + kt * 64 + c];
    }
    __syncthreads();
#pragma unroll
    for (int pass = 0; pass < 16; ++pass) {
        const int r = pass * 4 + r0;
        W1T[(size_t)(kt * 64 + r) * 512 + jt * 64 + c] = tile[c][r];
    }
}

// ---------------------------------------------------------------------------
// Kernel 4 (NEW): layer-1 split-K GEMM on W1T — coalesced weight reads
// (lanes along j), freq tile in LDS (broadcast), 512 blocks (2 waves/SIMD).
// Block: kq (128 k) x jh (256 j) x nb (4 n). Thread: 1 j, 4 n accumulators.
// ---------------------------------------------------------------------------
__global__ __launch_bounds__(256) void k_l1(const float* __restrict__ ws_ro,
                                            float* __restrict__ ws) {
    const int kq = blockIdx.x;   // 0..7
    const int jh = blockIdx.y;   // 0..1
    const int nb = blockIdx.z;   // 0..31
    const int tid = threadIdx.x;
    const int j = jh * 256 + tid;

    __shared__ float fq[4][128];
    {
        const float* FREQ = ws_ro + OFF_FREQ;
#pragma unroll
        for (int v = 0; v < 2; ++v) {
            const int idx = v * 256 + tid;          // 0..511
            const int m = idx >> 7, kk = idx & 127;
            fq[m][kk] = FREQ[(size_t)(nb * 4 + m) * 1024 + kq * 128 + kk];
        }
    }
    __syncthreads();

    const float* W1T = ws_ro + OFF_W1T + (size_t)kq * 128 * 512 + j;
    float a0 = 0.f, a1 = 0.f, a2 = 0.f, a3 = 0.f;
#pragma unroll 4
    for (int k = 0; k < 128; ++k) {
        const float w = W1T[(size_t)k * 512];       // coalesced along j
        a0 = fmaf(w, fq[0][k], a0);
        a1 = fmaf(w, fq[1][k], a1);
        a2 = fmaf(w, fq[2][k], a2);
        a3 = fmaf(w, fq[3][k], a3);
    }

    float* P1 = ws + OFF_P1 + (size_t)kq * (NN * H1D);
    P1[(size_t)(nb * 4 + 0) * H1D + j] = a0;
    P1[(size_t)(nb * 4 + 1) * H1D + j] = a1;
    P1[(size_t)(nb * 4 + 2) * H1D + j] = a2;
    P1[(size_t)(nb * 4 + 3) * H1D + j] = a3;
}

// ---------------------------------------------------------------------------
// Kernel 5: combine layer-1 split-K partials + bias + sigmoid -> h1
// ---------------------------------------------------------------------------
__global__ __launch_bounds__(256) void k_l1c(const float* __restrict__ b1,
                                             float* __restrict__ ws) {
    const int tid = blockIdx.x * 256 + threadIdx.x;   // = n*H1D + j
    const int j = tid & (H1D - 1);
    float s = b1[j];
#pragma unroll
    for (int kq = 0; kq < KQN; ++kq) s += ws[OFF_P1 + (size_t)kq * (NN * H1D) + tid];
    ws[OFF_H1 + tid] = 1.0f / (1.0f + __expf(-s));
}

// ---------------------------------------------------------------------------
// Kernel 6: fused layers 2+3 (round-1 verbatim)
// ---------------------------------------------------------------------------
__global__ __launch_bounds__(128) void k_l23(const float* __restrict__ W2,
                                             const float* __restrict__ b2,
                                             const float* __restrict__ W3,
                                             const float* __restrict__ b3,
                                             const float* __restrict__ ws,
                                             float* __restrict__ out) {
    const int n = blockIdx.x;
    const int j = threadIdx.x;   // 0..127

    __shared__ float4 h1l[128];  // h1 row (512 floats)
    __shared__ float  h2l[128];
    h1l[j] = ((const float4*)(ws + OFF_H1))[n * 128 + j];
    __syncthreads();

    const float4* W2v = (const float4*)W2;
    float a = b2[j];
#pragma unroll 4
    for (int k = 0; k < 128; ++k) {
        const float4 h = h1l[k];                    // broadcast
        const float4 w = W2v[(size_t)j * 128 + k];
        a = fmaf(h.x, w.x, fmaf(h.y, w.y, fmaf(h.z, w.z, fmaf(h.w, w.w, a))));
    }
    h2l[j] = 1.0f / (1.0f + __expf(-a));
    __syncthreads();

    if (j < OUTD) {
        float acc = b3[j];
        for (int q = 0; q < H2D; ++q) acc = fmaf(h2l[q], W3[j * H2D + q], acc);
        out[n * OUTD + j] = acc;
    }
}

extern "C" void kernel_launch(void* const* d_in, const int* in_sizes, int n_in,
                              void* d_out, int out_size, void* d_ws, size_t ws_size,
                              hipStream_t stream) {
    (void)in_sizes; (void)n_in; (void)out_size; (void)ws_size;
    const float* inp = (const float*)d_in[0];
    const float* W1  = (const float*)d_in[1];
    const float* b1  = (const float*)d_in[2];
    const float* W2  = (const float*)d_in[3];
    const float* b2  = (const float*)d_in[4];
    const float* W3  = (const float*)d_in[5];
    const float* b3  = (const float*)d_in[6];
    float* out = (float*)d_out;
    float* ws  = (float*)d_ws;

    k_trans   <<<dim3(8, 16),    dim3(256), 0, stream>>>(W1, ws);   // overlaps nothing it reads
    k_nudft   <<<dim3(TCH, NN),  dim3(256), 0, stream>>>(inp, ws);
    k_combine1<<<dim3(512),      dim3(256), 0, stream>>>(ws);
    k_l1      <<<dim3(8, 2, 32), dim3(256), 0, stream>>>(ws, ws);
    k_l1c     <<<dim3(256),      dim3(256), 0, stream>>>(b1, ws);
    k_l23     <<<dim3(128),      dim3(128), 0, stream>>>(W2, b2, W3, b3, ws, out);
}

// Round 8
// 54.553 us; speedup vs baseline: 2.0040x; 1.1322x over previous
//
#include <hip/hip_runtime.h>
#include <math.h>

// Problem constants (fixed by harness)
#define NN   128
#define TT   1024
#define SS   1024
#define H1D  512
#define H2D  128
#define OUTD 8
#define TCH  8      // t-chunks (TC=128 each, 2 halves of 64 per block)
#define TC   128
#define SPT  8      // s-values per thread (dual depth-3 rotation chains)
#define KQN  8      // layer-1 split-K chunks

// ws layout in floats (~11.3 MB)
#define OFF_RI   0                         // partials [ch][n][s] float2 (re,im)
#define OFF_FREQ (TCH*NN*SS*2)             // 2097152: freq [n][s]
#define OFF_P1   (OFF_FREQ + NN*SS)        // 2228224: P1 [8 kq][128 n][512 j]
#define OFF_H1   (OFF_P1 + KQN*NN*H1D)     // 2752512  (end 2818048)

__device__ __forceinline__ float cos_rev(float r) { return __builtin_amdgcn_cosf(r); } // cos(2*pi*r)
__device__ __forceinline__ float sin_rev(float r) { return __builtin_amdgcn_sinf(r); } // sin(2*pi*r)

// ---------------------------------------------------------------------------
// Kernel 1: partial NUDFT v2.
// Grid (TCH=8, NN); block 256 = 2 t-halves (64 t each) x 128 s-lanes.
// Thread owns 8 consecutive s as TWO depth-3 rotation chains seeded from ONE
// hw sincos: chain A = s0..s0+3 (rotate by 2*pi*df each step), chain B =
// s0+4..s0+7 (seed = one rotation by 2*pi*4df, precomputed in LDS).
// Cross-half LDS reduction -> one partial chunk per block (8 total).
// Exact mod-1 as validated in rounds 1-7 (absmax 0.0039).
// ---------------------------------------------------------------------------
__global__ __launch_bounds__(256) void k_nudft(const float* __restrict__ inp,
                                               float* __restrict__ ws) {
    const int tc  = blockIdx.x;    // 0..7
    const int n   = blockIdx.y;    // 0..127
    const int tid = threadIdx.x;
    const int th  = tid >> 7;      // t-half 0/1
    const int sl  = tid & 127;     // s-lane

    __shared__ float4 shA[TC];     // {frac(day), x, cos(2pi d), sin(2pi d)}
    __shared__ float2 shB[TC];     // {cos(2pi 4d), sin(2pi 4d)}
    __shared__ float2 red[SPT][128];
    if (tid < TC) {
        const float* p = inp + (size_t)(n * TT + tc * TC + tid) * 3;
        const float x  = p[0];
        const float d  = p[2];
        const float df = d - floorf(d);            // exact for |d| < 2^23
        float r4 = 4.0f * df;                      // exact (x4)
        r4 -= floorf(r4);
        shA[tid] = make_float4(df, x, cos_rev(df), sin_rev(df));
        shB[tid] = make_float2(cos_rev(r4), sin_rev(r4));
    }
    __syncthreads();

    const float s0f = (float)(sl * SPT);
    float2 acc[SPT];
#pragma unroll
    for (int q = 0; q < SPT; ++q) acc[q] = make_float2(0.f, 0.f);

#pragma unroll 2
    for (int i = 0; i < 64; ++i) {
        const int idx = th * 64 + i;
        const float4 v = shA[idx];                 // broadcast reads
        const float2 w = shB[idx];
        const float p   = s0f * v.x;
        const float plo = fmaf(s0f, v.x, -p);      // exact product residual
        const float r   = (p - floorf(p)) + plo;
        const float c  = cos_rev(r);
        const float sn = sin_rev(r);
        // chain B seed: rotate (c,sn) by 4*2*pi*df  (independent of chain A)
        float cB = fmaf(-sn, w.y, c * w.x);
        float sB = fmaf( c,  w.y, sn * w.x);
        // chain A: s0..s0+3
        float cA = c, sA = sn;
        acc[0].x = fmaf(v.y, cA, acc[0].x); acc[0].y = fmaf(v.y, sA, acc[0].y);
        acc[4].x = fmaf(v.y, cB, acc[4].x); acc[4].y = fmaf(v.y, sB, acc[4].y);
#pragma unroll
        for (int q = 1; q < 4; ++q) {
            const float cA2 = fmaf(-sA, v.w, cA * v.z);
            const float sA2 = fmaf( cA, v.w, sA * v.z);
            const float cB2 = fmaf(-sB, v.w, cB * v.z);
            const float sB2 = fmaf( cB, v.w, sB * v.z);
            cA = cA2; sA = sA2; cB = cB2; sB = sB2;
            acc[q].x     = fmaf(v.y, cA, acc[q].x);
            acc[q].y     = fmaf(v.y, sA, acc[q].y);
            acc[q + 4].x = fmaf(v.y, cB, acc[q + 4].x);
            acc[q + 4].y = fmaf(v.y, sB, acc[q + 4].y);
        }
    }

    // cross-half reduction: half 1 deposits, half 0 adds and writes.
    if (th == 1) {
#pragma unroll
        for (int q = 0; q < SPT; ++q) red[q][sl] = acc[q];
    }
    __syncthreads();
    if (th == 0) {
        float4* RI = (float4*)(ws + OFF_RI) +
                     ((((size_t)(tc * NN + n)) * SS + sl * SPT) >> 1);
#pragma unroll
        for (int q = 0; q < SPT / 2; ++q) {
            const float2 r0 = red[2*q][sl], r1 = red[2*q+1][sl];
            RI[q] = make_float4(acc[2*q].x + r0.x, acc[2*q].y + r0.y,
                                acc[2*q+1].x + r1.x, acc[2*q+1].y + r1.y);
        }
    }
}

// ---------------------------------------------------------------------------
// Kernel 2: combine t-chunk partials -> frequential = sqrt(re^2 + im^2)
// ---------------------------------------------------------------------------
__global__ __launch_bounds__(256) void k_combine1(float* __restrict__ ws) {
    const int idx = blockIdx.x * 256 + threadIdx.x;   // = n*SS + s
    const float2* P = (const float2*)(ws + OFF_RI);
    float re = 0.f, im = 0.f;
#pragma unroll
    for (int ch = 0; ch < TCH; ++ch) {
        const float2 v = P[(size_t)ch * (NN * SS) + idx];
        re += v.x; im += v.y;
    }
    ws[OFF_FREQ + idx] = sqrtf(fmaf(re, re, im * im));
}

// ---------------------------------------------------------------------------
// Kernel 3: layer-1 split-K partial GEMM (round-1 structure, K-chunks 4->8:
// 512 blocks = 2 waves/SIMD). W1 reads unchanged (L2 absorbs overfetch).
// ---------------------------------------------------------------------------
__global__ __launch_bounds__(256) void k_l1p(const float* __restrict__ W1,
                                             float* __restrict__ ws) {
    const int kq = blockIdx.x;   // 0..7   k-chunk of 128
    const int jq = blockIdx.y;   // 0..3   j-chunk of 128
    const int nb = blockIdx.z;   // 0..15  n-chunk of 8
    const int tid = threadIdx.x;

    __shared__ float4 Al[8][32];  // 8 n-rows x 128 k (as float4)
    const float4* FQ = (const float4*)(ws + OFF_FREQ);
    {
        const int row = tid >> 5, c4 = tid & 31;
        Al[row][c4] = FQ[(nb * 8 + row) * 256 + kq * 32 + c4];
    }
    __syncthreads();

    const int jl = tid & 127, ng = tid >> 7;
    const int j = jq * 128 + jl;
    const float4* W1v = (const float4*)W1;
    float a0 = 0.f, a1 = 0.f, a2 = 0.f, a3 = 0.f;
#pragma unroll 4
    for (int k4 = 0; k4 < 32; ++k4) {
        const float4 w  = W1v[(size_t)j * 256 + kq * 32 + k4];
        const float4 x0 = Al[ng * 4 + 0][k4];
        const float4 x1 = Al[ng * 4 + 1][k4];
        const float4 x2 = Al[ng * 4 + 2][k4];
        const float4 x3 = Al[ng * 4 + 3][k4];
        a0 = fmaf(x0.x, w.x, fmaf(x0.y, w.y, fmaf(x0.z, w.z, fmaf(x0.w, w.w, a0))));
        a1 = fmaf(x1.x, w.x, fmaf(x1.y, w.y, fmaf(x1.z, w.z, fmaf(x1.w, w.w, a1))));
        a2 = fmaf(x2.x, w.x, fmaf(x2.y, w.y, fmaf(x2.z, w.z, fmaf(x2.w, w.w, a2))));
        a3 = fmaf(x3.x, w.x, fmaf(x3.y, w.y, fmaf(x3.z, w.z, fmaf(x3.w, w.w, a3))));
    }
    float* P1 = ws + OFF_P1;
    const float acc[4] = {a0, a1, a2, a3};
#pragma unroll
    for (int i = 0; i < 4; ++i)
        P1[((size_t)(kq * NN + nb * 8 + ng * 4 + i)) * H1D + j] = acc[i];
}

// ---------------------------------------------------------------------------
// Kernel 4: combine layer-1 split-K partials + bias + sigmoid -> h1
// ---------------------------------------------------------------------------
__global__ __launch_bounds__(256) void k_l1c(const float* __restrict__ b1,
                                             float* __restrict__ ws) {
    const int tid = blockIdx.x * 256 + threadIdx.x;   // = n*H1D + j
    const int j = tid & (H1D - 1);
    float s = b1[j];
#pragma unroll
    for (int kq = 0; kq < KQN; ++kq) s += ws[OFF_P1 + (size_t)kq * (NN * H1D) + tid];
    ws[OFF_H1 + tid] = 1.0f / (1.0f + __expf(-s));
}

// ---------------------------------------------------------------------------
// Kernel 5: fused layers 2+3 (round-1 verbatim)
// ---------------------------------------------------------------------------
__global__ __launch_bounds__(128) void k_l23(const float* __restrict__ W2,
                                             const float* __restrict__ b2,
                                             const float* __restrict__ W3,
                                             const float* __restrict__ b3,
                                             const float* __restrict__ ws,
                                             float* __restrict__ out) {
    const int n = blockIdx.x;
    const int j = threadIdx.x;   // 0..127

    __shared__ float4 h1l[128];  // h1 row (512 floats)
    __shared__ float  h2l[128];
    h1l[j] = ((const float4*)(ws + OFF_H1))[n * 128 + j];
    __syncthreads();

    const float4* W2v = (const float4*)W2;
    float a = b2[j];
#pragma unroll 4
    for (int k = 0; k < 128; ++k) {
        const float4 h = h1l[k];                    // broadcast
        const float4 w = W2v[(size_t)j * 128 + k];
        a = fmaf(h.x, w.x, fmaf(h.y, w.y, fmaf(h.z, w.z, fmaf(h.w, w.w, a))));
    }
    h2l[j] = 1.0f / (1.0f + __expf(-a));
    __syncthreads();

    if (j < OUTD) {
        float acc = b3[j];
        for (int q = 0; q < H2D; ++q) acc = fmaf(h2l[q], W3[j * H2D + q], acc);
        out[n * OUTD + j] = acc;
    }
}

extern "C" void kernel_launch(void* const* d_in, const int* in_sizes, int n_in,
                              void* d_out, int out_size, void* d_ws, size_t ws_size,
                              hipStream_t stream) {
    (void)in_sizes; (void)n_in; (void)out_size; (void)ws_size;
    const float* inp = (const float*)d_in[0];
    const float* W1  = (const float*)d_in[1];
    const float* b1  = (const float*)d_in[2];
    const float* W2  = (const float*)d_in[3];
    const float* b2  = (const float*)d_in[4];
    const float* W3  = (const float*)d_in[5];
    const float* b3  = (const float*)d_in[6];
    float* out = (float*)d_out;
    float* ws  = (float*)d_ws;

    k_nudft   <<<dim3(TCH, NN), dim3(256), 0, stream>>>(inp, ws);
    k_combine1<<<dim3(512),     dim3(256), 0, stream>>>(ws);
    k_l1p     <<<dim3(8, 4, 16),dim3(256), 0, stream>>>(W1, ws);
    k_l1c     <<<dim3(256),     dim3(256), 0, stream>>>(b1, ws);
    k_l23     <<<dim3(128),     dim3(128), 0, stream>>>(W2, b2, W3, b3, ws, out);
}